// Round 1
// baseline (605.106 us; speedup 1.0000x reference)
//
#include <hip/hip_runtime.h>

#define NRES 512
#define N2   262144   // 512*512

typedef __attribute__((ext_vector_type(8))) short s16x8;
typedef __attribute__((ext_vector_type(4))) float f32x4;

__device__ __forceinline__ ushort f2bf(float x){
  union { float f; unsigned u; } v; v.f = x;
  unsigned r = (v.u + 0x7FFFu + ((v.u >> 16) & 1u)) >> 16;
  return (ushort)r;
}
__device__ __forceinline__ float bf2f(ushort h){
  union { unsigned u; float f; } v; v.u = ((unsigned)h) << 16; return v.f;
}
__device__ __forceinline__ float sigm(float x){ return 1.0f / (1.0f + __expf(-x)); }

__device__ __forceinline__ void gld_lds16(const void* g, void* lds){
  __builtin_amdgcn_global_load_lds((const __attribute__((address_space(1))) void*)g,
                                   (__attribute__((address_space(3))) void*)lds, 16, 0, 0);
}

// -------------------- kernel 0: weight transpose+convert --------------------
// Wt[m][n][k] = bf16(W_m[k][n]),  m in {lp, lg, rp, rg, gate, out}
__global__ void k0_prep(const float* __restrict__ lp, const float* __restrict__ lg,
                        const float* __restrict__ rp, const float* __restrict__ rg,
                        const float* __restrict__ gw, const float* __restrict__ ow,
                        ushort* __restrict__ Wt)
{
  const float* srcs[6] = {lp, lg, rp, rg, gw, ow};
  const float* wsrc = srcs[blockIdx.x];
  ushort* dst = Wt + blockIdx.x * 16384;
  for (int f = threadIdx.x; f < 16384; f += blockDim.x){
    int n = f >> 7, k = f & 127;
    dst[f] = f2bf(wsrc[k * 128 + n]);
  }
}

// -------------------- shared GEMM helpers (128x128x128, 4 waves) -----------
__device__ __forceinline__ void stage_w(const ushort* __restrict__ Wt_m,
                                        ushort* Wlds, int t)
{
  #pragma unroll
  for (int u = 0; u < 8; ++u){
    int f = t + u * 256;          // bf16x8 unit index, 2048 total
    int n = f >> 4, k8 = f & 15;
    *(s16x8*)&Wlds[n * 136 + k8 * 8] = *(const s16x8*)(Wt_m + f * 8);
  }
}

__device__ __forceinline__ void do_gemm128(const ushort* Alds, const ushort* Wlds,
                                           int wr, int wc, int cl, int h,
                                           f32x4 acc[4][4])
{
  #pragma unroll
  for (int ks = 0; ks < 4; ++ks){
    s16x8 a[4], b[4];
    #pragma unroll
    for (int m = 0; m < 4; ++m)
      a[m] = *(const s16x8*)&Alds[(wr*64 + m*16 + cl) * 136 + ks*32 + h*8];
    #pragma unroll
    for (int n = 0; n < 4; ++n)
      b[n] = *(const s16x8*)&Wlds[(wc*64 + n*16 + cl) * 136 + ks*32 + h*8];
    #pragma unroll
    for (int m = 0; m < 4; ++m)
      #pragma unroll
      for (int n = 0; n < 4; ++n)
        acc[m][n] = __builtin_amdgcn_mfma_f32_16x16x32_bf16(a[m], b[n], acc[m][n], 0, 0, 0);
  }
}

// -------------------- kernel 1: LN + 5 projections --------------------------
__global__ __launch_bounds__(256) void k1_proj(
    const float* __restrict__ act,  const float* __restrict__ mask,
    const float* __restrict__ ln_g, const float* __restrict__ ln_b,
    const float* __restrict__ lp_b, const float* __restrict__ lg_b,
    const float* __restrict__ rp_b, const float* __restrict__ rg_b,
    const float* __restrict__ gate_b, const ushort* __restrict__ Wt,
    ushort* __restrict__ leftg, ushort* __restrict__ rightg,
    ushort* __restrict__ gateg)
{
  __shared__ ushort Alds[128 * 136];
  __shared__ ushort Wlds[128 * 136];
  const int t  = threadIdx.x;
  const int p0 = blockIdx.x * 128;

  // ---- phase A: input layernorm -> bf16 A tile in LDS ----
  {
    const int g = t >> 5, j = t & 31;
    const float4 gv = *(const float4*)(ln_g + j * 4);
    const float4 bv = *(const float4*)(ln_b + j * 4);
    #pragma unroll
    for (int i = 0; i < 16; ++i){
      const int r = g + (i << 3);
      float4 v = *(const float4*)(act + (size_t)(p0 + r) * 128 + j * 4);
      float s = v.x + v.y + v.z + v.w;
      float q = v.x*v.x + v.y*v.y + v.z*v.z + v.w*v.w;
      #pragma unroll
      for (int m = 1; m < 32; m <<= 1){ s += __shfl_xor(s, m); q += __shfl_xor(q, m); }
      float mu = s * (1.0f / 128.0f);
      float rs = rsqrtf(q * (1.0f / 128.0f) - mu * mu + 1e-5f);
      ushort4 o;
      o.x = f2bf((v.x - mu) * rs * gv.x + bv.x);
      o.y = f2bf((v.y - mu) * rs * gv.y + bv.y);
      o.z = f2bf((v.z - mu) * rs * gv.z + bv.z);
      o.w = f2bf((v.w - mu) * rs * gv.w + bv.w);
      *(ushort4*)&Alds[r * 136 + j * 4] = o;
    }
  }
  __syncthreads();

  const int lane = t & 63, w = t >> 6;
  const int wr = w >> 1, wc = w & 1;
  const int cl = lane & 15, h = lane >> 4;

  f32x4 accP[4][4], accG[4][4];
  const f32x4 z = {0.f, 0.f, 0.f, 0.f};

  const float* pbias[2] = {lp_b, rp_b};
  const float* gbias[2] = {lg_b, rg_b};
  ushort* dsts[2] = {leftg, rightg};

  // ---- left & right: (mask * (a@Wp + bp)) * sigmoid(a@Wg + bg), ch-major ----
  for (int grp = 0; grp < 2; ++grp){
    const int s0 = grp * 2;
    stage_w(Wt + (size_t)s0 * 16384, Wlds, t);
    __syncthreads();
    #pragma unroll
    for (int m = 0; m < 4; ++m)
      #pragma unroll
      for (int n = 0; n < 4; ++n) accP[m][n] = z;
    do_gemm128(Alds, Wlds, wr, wc, cl, h, accP);
    __syncthreads();
    stage_w(Wt + (size_t)(s0 + 1) * 16384, Wlds, t);
    __syncthreads();
    #pragma unroll
    for (int m = 0; m < 4; ++m)
      #pragma unroll
      for (int n = 0; n < 4; ++n) accG[m][n] = z;
    do_gemm128(Alds, Wlds, wr, wc, cl, h, accG);
    __syncthreads();   // before reusing Wlds as transpose scratch

    float mk[4][4];
    #pragma unroll
    for (int m = 0; m < 4; ++m)
      #pragma unroll
      for (int r = 0; r < 4; ++r)
        mk[m][r] = mask[p0 + wr*64 + m*16 + h*4 + r];
    float pb[4], gb[4];
    #pragma unroll
    for (int n = 0; n < 4; ++n){
      int c = wc*64 + n*16 + cl;
      pb[n] = pbias[grp][c];
      gb[n] = gbias[grp][c];
    }
    #pragma unroll
    for (int m = 0; m < 4; ++m)
      #pragma unroll
      for (int n = 0; n < 4; ++n){
        int c = wc*64 + n*16 + cl;
        #pragma unroll
        for (int r = 0; r < 4; ++r){
          int pl = wr*64 + m*16 + h*4 + r;
          float val = mk[m][r] * (accP[m][n][r] + pb[n]) * sigm(accG[m][n][r] + gb[n]);
          Wlds[c * 136 + pl] = f2bf(val);   // transpose to [c][p]
        }
      }
    __syncthreads();
    // coalesced channel-major store: dst[c*N2 + p0 + p]
    ushort* dst = dsts[grp];
    #pragma unroll
    for (int u = 0; u < 8; ++u){
      int f = t + u * 256;
      int c = f >> 4, p8 = f & 15;
      *(s16x8*)(dst + (size_t)c * N2 + p0 + p8 * 8) =
          *(const s16x8*)&Wlds[c * 136 + p8 * 8];
    }
    __syncthreads();
  }

  // ---- gate: sigmoid(a@gate_w + gate_b), pair-major [p][c] ----
  stage_w(Wt + (size_t)4 * 16384, Wlds, t);
  __syncthreads();
  #pragma unroll
  for (int m = 0; m < 4; ++m)
    #pragma unroll
    for (int n = 0; n < 4; ++n) accP[m][n] = z;
  do_gemm128(Alds, Wlds, wr, wc, cl, h, accP);
  __syncthreads();
  {
    float gbv[4];
    #pragma unroll
    for (int n = 0; n < 4; ++n) gbv[n] = gate_b[wc*64 + n*16 + cl];
    #pragma unroll
    for (int m = 0; m < 4; ++m)
      #pragma unroll
      for (int n = 0; n < 4; ++n){
        int c = wc*64 + n*16 + cl;
        #pragma unroll
        for (int r = 0; r < 4; ++r){
          int pl = wr*64 + m*16 + h*4 + r;
          Wlds[pl * 136 + c] = f2bf(sigm(accP[m][n][r] + gbv[n]));
        }
      }
  }
  __syncthreads();
  #pragma unroll
  for (int u = 0; u < 8; ++u){
    int f = t + u * 256;
    int p = f >> 4, c8 = f & 15;
    *(s16x8*)(gateg + (size_t)(p0 + p) * 128 + c8 * 8) =
        *(const s16x8*)&Wlds[p * 136 + c8 * 8];
  }
}

// -------------------- kernel 2: per-channel NT GEMM (triangle) --------------
// X[c][i][j] = sum_k left[c][i][k] * right[c][j][k]
__global__ __launch_bounds__(256) void k2_tri(const ushort* __restrict__ leftg,
                                              const ushort* __restrict__ rightg,
                                              float* __restrict__ X)
{
  __shared__ ushort Ab[128 * 32];   // [row][k] bf16, rows 64B
  __shared__ ushort Bb[128 * 32];
  const int t = threadIdx.x, lane = t & 63, w = t >> 6;
  const int b = blockIdx.x;
  const int c = b & 127, tile = b >> 7;          // all tiles of a channel on one XCD
  const int tm = (tile >> 2) * 128, tn = (tile & 3) * 128;
  const ushort* Lc = leftg  + (size_t)c * N2;
  const ushort* Rc = rightg + (size_t)c * N2;
  float* Xc = X + (size_t)c * N2;
  const int wr = w >> 1, wc = w & 1, cl = lane & 15, h = lane >> 4;

  f32x4 acc[4][4];
  const f32x4 z = {0.f, 0.f, 0.f, 0.f};
  #pragma unroll
  for (int m = 0; m < 4; ++m)
    #pragma unroll
    for (int n = 0; n < 4; ++n) acc[m][n] = z;

  for (int kt = 0; kt < 16; ++kt){
    __syncthreads();
    #pragma unroll
    for (int s = 0; s < 2; ++s){
      const int q = w + 4 * s;                 // 8 chunks of 1KB per tile
      const int o = q * 1024 + lane * 16;
      const int row = o >> 6, kb = o & 63;
      gld_lds16((const char*)Lc + (size_t)(tm + row) * 1024 + kt * 64 + kb,
                (char*)Ab + q * 1024);
      gld_lds16((const char*)Rc + (size_t)(tn + row) * 1024 + kt * 64 + kb,
                (char*)Bb + q * 1024);
    }
    __syncthreads();
    s16x8 a[4], bf[4];
    #pragma unroll
    for (int m = 0; m < 4; ++m)
      a[m] = *(const s16x8*)&Ab[(wr*64 + m*16 + cl) * 32 + h * 8];
    #pragma unroll
    for (int n = 0; n < 4; ++n)
      bf[n] = *(const s16x8*)&Bb[(wc*64 + n*16 + cl) * 32 + h * 8];
    #pragma unroll
    for (int m = 0; m < 4; ++m)
      #pragma unroll
      for (int n = 0; n < 4; ++n)
        acc[m][n] = __builtin_amdgcn_mfma_f32_16x16x32_bf16(a[m], bf[n], acc[m][n], 0, 0, 0);
  }

  #pragma unroll
  for (int m = 0; m < 4; ++m)
    #pragma unroll
    for (int n = 0; n < 4; ++n)
      #pragma unroll
      for (int r = 0; r < 4; ++r)
        Xc[(size_t)(tm + wr*64 + m*16 + h*4 + r) * NRES + tn + wc*64 + n*16 + cl] =
            acc[m][n][r];
}

// -------------------- kernel 3: LN + out projection * gate ------------------
__global__ __launch_bounds__(256) void k3_out(
    const float* __restrict__ X, const ushort* __restrict__ gateg,
    const ushort* __restrict__ Wt5,
    const float* __restrict__ ln_g, const float* __restrict__ ln_b,
    const float* __restrict__ ob, float* __restrict__ out)
{
  __shared__ ushort Alds[128 * 136];
  __shared__ ushort Wlds[128 * 136];
  __shared__ float part[8][2][128];
  __shared__ float stat[2][128];
  const int t = threadIdx.x;
  const int p0 = blockIdx.x * 128;
  const int g = t >> 5, j = t & 31;

  float4 xv[16];
  float s0 = 0, s1 = 0, s2 = 0, s3 = 0, q0 = 0, q1 = 0, q2 = 0, q3 = 0;
  #pragma unroll
  for (int i = 0; i < 16; ++i){
    const int cch = g + (i << 3);
    xv[i] = *(const float4*)(X + (size_t)cch * N2 + p0 + j * 4);
    s0 += xv[i].x; q0 += xv[i].x * xv[i].x;
    s1 += xv[i].y; q1 += xv[i].y * xv[i].y;
    s2 += xv[i].z; q2 += xv[i].z * xv[i].z;
    s3 += xv[i].w; q3 += xv[i].w * xv[i].w;
  }
  part[g][0][j*4+0] = s0; part[g][0][j*4+1] = s1;
  part[g][0][j*4+2] = s2; part[g][0][j*4+3] = s3;
  part[g][1][j*4+0] = q0; part[g][1][j*4+1] = q1;
  part[g][1][j*4+2] = q2; part[g][1][j*4+3] = q3;
  __syncthreads();
  if (t < 128){
    float s = 0, q = 0;
    #pragma unroll
    for (int gg = 0; gg < 8; ++gg){ s += part[gg][0][t]; q += part[gg][1][t]; }
    float mu = s * (1.0f / 128.0f);
    float rs = rsqrtf(q * (1.0f / 128.0f) - mu * mu + 1e-5f);
    stat[0][t] = mu; stat[1][t] = rs;
  }
  __syncthreads();
  #pragma unroll
  for (int i = 0; i < 16; ++i){
    const int cch = g + (i << 3);
    const float gc = ln_g[cch], bc = ln_b[cch];
    const int p = j * 4;
    Alds[(p+0) * 136 + cch] = f2bf((xv[i].x - stat[0][p+0]) * stat[1][p+0] * gc + bc);
    Alds[(p+1) * 136 + cch] = f2bf((xv[i].y - stat[0][p+1]) * stat[1][p+1] * gc + bc);
    Alds[(p+2) * 136 + cch] = f2bf((xv[i].z - stat[0][p+2]) * stat[1][p+2] * gc + bc);
    Alds[(p+3) * 136 + cch] = f2bf((xv[i].w - stat[0][p+3]) * stat[1][p+3] * gc + bc);
  }
  stage_w(Wt5, Wlds, t);
  __syncthreads();

  const int lane = t & 63, w = t >> 6;
  const int wr = w >> 1, wc = w & 1, cl = lane & 15, h = lane >> 4;
  f32x4 acc[4][4];
  const f32x4 z = {0.f, 0.f, 0.f, 0.f};
  #pragma unroll
  for (int m = 0; m < 4; ++m)
    #pragma unroll
    for (int n = 0; n < 4; ++n) acc[m][n] = z;
  do_gemm128(Alds, Wlds, wr, wc, cl, h, acc);

  float obv[4];
  #pragma unroll
  for (int n = 0; n < 4; ++n) obv[n] = ob[wc*64 + n*16 + cl];
  #pragma unroll
  for (int m = 0; m < 4; ++m)
    #pragma unroll
    for (int n = 0; n < 4; ++n){
      const int cc = wc*64 + n*16 + cl;
      #pragma unroll
      for (int r = 0; r < 4; ++r){
        const size_t p = p0 + wr*64 + m*16 + h*4 + r;
        out[p * 128 + cc] = (acc[m][n][r] + obv[n]) * bf2f(gateg[p * 128 + cc]);
      }
    }
}

// -------------------- launcher ----------------------------------------------
extern "C" void kernel_launch(void* const* d_in, const int* in_sizes, int n_in,
                              void* d_out, int out_size, void* d_ws, size_t ws_size,
                              hipStream_t stream)
{
  const float* act    = (const float*)d_in[0];
  const float* mask   = (const float*)d_in[1];
  const float* ln_in_g = (const float*)d_in[2];
  const float* ln_in_b = (const float*)d_in[3];
  const float* lp_w = (const float*)d_in[4];
  const float* lp_b = (const float*)d_in[5];
  const float* rp_w = (const float*)d_in[6];
  const float* rp_b = (const float*)d_in[7];
  const float* lg_w = (const float*)d_in[8];
  const float* lg_b = (const float*)d_in[9];
  const float* rg_w = (const float*)d_in[10];
  const float* rg_b = (const float*)d_in[11];
  const float* ln_c_g = (const float*)d_in[12];
  const float* ln_c_b = (const float*)d_in[13];
  const float* out_w  = (const float*)d_in[14];
  const float* out_b  = (const float*)d_in[15];
  const float* gate_w = (const float*)d_in[16];
  const float* gate_b = (const float*)d_in[17];
  float* outp = (float*)d_out;

  char* ws = (char*)d_ws;
  ushort* Wt     = (ushort*)(ws);                                  // 196608 B
  ushort* leftg  = (ushort*)(ws + 196608);                         // 64 MB
  ushort* rightg = (ushort*)(ws + 196608 + 67108864ull);           // 64 MB
  ushort* gateg  = (ushort*)(ws + 196608 + 2ull * 67108864ull);    // 64 MB
  float*  X      = (float*) (ws + 196608 + 3ull * 67108864ull);    // 128 MB

  k0_prep<<<dim3(6), dim3(256), 0, stream>>>(lp_w, lg_w, rp_w, rg_w, gate_w, out_w, Wt);
  k1_proj<<<dim3(2048), dim3(256), 0, stream>>>(act, mask, ln_in_g, ln_in_b,
                                                lp_b, lg_b, rp_b, rg_b, gate_b,
                                                Wt, leftg, rightg, gateg);
  k2_tri<<<dim3(2048), dim3(256), 0, stream>>>(leftg, rightg, X);
  k3_out<<<dim3(2048), dim3(256), 0, stream>>>(X, gateg, Wt + 5 * 16384,
                                               ln_c_g, ln_c_b, out_b, outp);
}

// Round 2
// 580.496 us; speedup vs baseline: 1.0424x; 1.0424x over previous
//
#include <hip/hip_runtime.h>

#define NRES 512
#define N2   262144   // 512*512

typedef __attribute__((ext_vector_type(8))) short s16x8;
typedef __attribute__((ext_vector_type(4))) float f32x4;

__device__ __forceinline__ ushort f2bf(float x){
  union { float f; unsigned u; } v; v.f = x;
  unsigned r = (v.u + 0x7FFFu + ((v.u >> 16) & 1u)) >> 16;
  return (ushort)r;
}
__device__ __forceinline__ float bf2f(ushort h){
  union { unsigned u; float f; } v; v.u = ((unsigned)h) << 16; return v.f;
}
__device__ __forceinline__ float sigm(float x){ return 1.0f / (1.0f + __expf(-x)); }

__device__ __forceinline__ void gld_lds16(const void* g, void* lds){
  __builtin_amdgcn_global_load_lds((const __attribute__((address_space(1))) void*)g,
                                   (__attribute__((address_space(3))) void*)lds, 16, 0, 0);
}

// -------------------- kernel 0: weight transpose+convert --------------------
// Wt[m][n][k] = bf16(W_m[k][n]),  m in {lp, lg, rp, rg, gate, out}
__global__ void k0_prep(const float* __restrict__ lp, const float* __restrict__ lg,
                        const float* __restrict__ rp, const float* __restrict__ rg,
                        const float* __restrict__ gw, const float* __restrict__ ow,
                        ushort* __restrict__ Wt)
{
  const float* srcs[6] = {lp, lg, rp, rg, gw, ow};
  const float* wsrc = srcs[blockIdx.x];
  ushort* dst = Wt + blockIdx.x * 16384;
  for (int f = threadIdx.x; f < 16384; f += blockDim.x){
    int n = f >> 7, k = f & 127;
    dst[f] = f2bf(wsrc[k * 128 + n]);
  }
}

// -------------------- kernel 1: LN + 5 projections (1-barrier) --------------
// Each wave owns a 32-column slab of all 5 output matrices. Weights read
// directly from global (L2-resident, 192 KB). A-frags register-resident per
// 64-row half. left/right stored channel-major direct; gate via per-wave
// LDS scratch transpose to pair-major.
__global__ __launch_bounds__(256) void k1_proj(
    const float* __restrict__ act,  const float* __restrict__ mask,
    const float* __restrict__ ln_g, const float* __restrict__ ln_b,
    const float* __restrict__ lp_b, const float* __restrict__ lg_b,
    const float* __restrict__ rp_b, const float* __restrict__ rg_b,
    const float* __restrict__ gate_b, const ushort* __restrict__ Wt,
    ushort* __restrict__ leftg, ushort* __restrict__ rightg,
    ushort* __restrict__ gateg)
{
  __shared__ ushort Alds[128 * 136];      // 34816 B
  __shared__ ushort Gscr[4][64 * 32];     // per-wave gate transpose, 16384 B
  const int t  = threadIdx.x;
  const int p0 = blockIdx.x * 128;

  // ---- phase A: input layernorm -> bf16 A tile in LDS ----
  {
    const int g = t >> 5, j = t & 31;
    const float4 gv = *(const float4*)(ln_g + j * 4);
    const float4 bv = *(const float4*)(ln_b + j * 4);
    #pragma unroll
    for (int i = 0; i < 16; ++i){
      const int r = g + (i << 3);
      float4 v = *(const float4*)(act + (size_t)(p0 + r) * 128 + j * 4);
      float s = v.x + v.y + v.z + v.w;
      float q = v.x*v.x + v.y*v.y + v.z*v.z + v.w*v.w;
      #pragma unroll
      for (int m = 1; m < 32; m <<= 1){ s += __shfl_xor(s, m); q += __shfl_xor(q, m); }
      float mu = s * (1.0f / 128.0f);
      float rs = rsqrtf(q * (1.0f / 128.0f) - mu * mu + 1e-5f);
      ushort4 o;
      o.x = f2bf((v.x - mu) * rs * gv.x + bv.x);
      o.y = f2bf((v.y - mu) * rs * gv.y + bv.y);
      o.z = f2bf((v.z - mu) * rs * gv.z + bv.z);
      o.w = f2bf((v.w - mu) * rs * gv.w + bv.w);
      *(ushort4*)&Alds[r * 136 + j * 4] = o;
    }
  }
  __syncthreads();      // the only barrier

  const int lane = t & 63, w = t >> 6;
  const int cl = lane & 15, h = lane >> 4;
  const f32x4 z = {0.f, 0.f, 0.f, 0.f};

  const float* pbias[2] = {lp_b, rp_b};
  const float* gbias[2] = {lg_b, rg_b};
  ushort* dsts[2] = {leftg, rightg};

  for (int mh = 0; mh < 2; ++mh){
    // A-fragments for rows [mh*64, mh*64+64), register-resident
    s16x8 a[4][4];
    #pragma unroll
    for (int m = 0; m < 4; ++m)
      #pragma unroll
      for (int ks = 0; ks < 4; ++ks)
        a[m][ks] = *(const s16x8*)&Alds[(mh*64 + m*16 + cl) * 136 + ks*32 + h*8];

    float mk[4][4];
    #pragma unroll
    for (int m = 0; m < 4; ++m)
      #pragma unroll
      for (int r = 0; r < 4; ++r)
        mk[m][r] = mask[p0 + mh*64 + m*16 + h*4 + r];

    // ---- left & right: mask * (a@Wp + bp) * sigmoid(a@Wg + bg) ----
    #pragma unroll
    for (int grp = 0; grp < 2; ++grp){
      ushort* dst = dsts[grp];
      #pragma unroll
      for (int rep = 0; rep < 2; ++rep){
        const int c0 = (w * 2 + rep) * 16;
        const ushort* WP = Wt + (size_t)(grp * 2) * 16384 + (size_t)(c0 + cl) * 128;
        const ushort* WG = WP + 16384;
        s16x8 bP[4], bG[4];
        #pragma unroll
        for (int ks = 0; ks < 4; ++ks){
          bP[ks] = *(const s16x8*)(WP + ks*32 + h*8);
          bG[ks] = *(const s16x8*)(WG + ks*32 + h*8);
        }
        f32x4 accP[4], accG[4];
        #pragma unroll
        for (int m = 0; m < 4; ++m){ accP[m] = z; accG[m] = z; }
        #pragma unroll
        for (int ks = 0; ks < 4; ++ks)
          #pragma unroll
          for (int m = 0; m < 4; ++m){
            accP[m] = __builtin_amdgcn_mfma_f32_16x16x32_bf16(a[m][ks], bP[ks], accP[m], 0, 0, 0);
            accG[m] = __builtin_amdgcn_mfma_f32_16x16x32_bf16(a[m][ks], bG[ks], accG[m], 0, 0, 0);
          }
        const float pb = pbias[grp][c0 + cl];
        const float gb = gbias[grp][c0 + cl];
        #pragma unroll
        for (int m = 0; m < 4; ++m){
          ushort4 o;
          o.x = f2bf(mk[m][0] * (accP[m][0] + pb) * sigm(accG[m][0] + gb));
          o.y = f2bf(mk[m][1] * (accP[m][1] + pb) * sigm(accG[m][1] + gb));
          o.z = f2bf(mk[m][2] * (accP[m][2] + pb) * sigm(accG[m][2] + gb));
          o.w = f2bf(mk[m][3] * (accP[m][3] + pb) * sigm(accG[m][3] + gb));
          // channel-major direct store; 4 m-frags fill each 128B line in L2
          *(ushort4*)(dst + (size_t)(c0 + cl) * N2 + p0 + mh*64 + m*16 + h*4) = o;
        }
      }
    }

    // ---- gate: sigmoid(a@gate_w + gate_b), pair-major via LDS transpose ----
    #pragma unroll
    for (int rep = 0; rep < 2; ++rep){
      const int c0 = (w * 2 + rep) * 16;
      const ushort* W5 = Wt + (size_t)4 * 16384 + (size_t)(c0 + cl) * 128;
      s16x8 b[4];
      #pragma unroll
      for (int ks = 0; ks < 4; ++ks)
        b[ks] = *(const s16x8*)(W5 + ks*32 + h*8);
      f32x4 acc[4];
      #pragma unroll
      for (int m = 0; m < 4; ++m) acc[m] = z;
      #pragma unroll
      for (int ks = 0; ks < 4; ++ks)
        #pragma unroll
        for (int m = 0; m < 4; ++m)
          acc[m] = __builtin_amdgcn_mfma_f32_16x16x32_bf16(a[m][ks], b[ks], acc[m], 0, 0, 0);
      const float gbv = gate_b[c0 + cl];
      #pragma unroll
      for (int m = 0; m < 4; ++m)
        #pragma unroll
        for (int r = 0; r < 4; ++r)
          Gscr[w][(m*16 + h*4 + r) * 32 + rep*16 + cl] = f2bf(sigm(acc[m][r] + gbv));
    }
    // per-wave readback (in-wave lgkmcnt, no barrier) + 64B-chunk stores
    #pragma unroll
    for (int u = 0; u < 4; ++u){
      const int f = u * 64 + lane;
      const int p = f >> 2, ci = f & 3;
      *(s16x8*)(gateg + (size_t)(p0 + mh*64 + p) * 128 + w*32 + ci*8) =
          *(const s16x8*)&Gscr[w][p*32 + ci*8];
    }
  }
}

// -------------------- kernel 2: per-channel NT GEMM (triangle) --------------
// X[c][i][j] = sum_k left[c][i][k] * right[c][j][k]
__global__ __launch_bounds__(256) void k2_tri(const ushort* __restrict__ leftg,
                                              const ushort* __restrict__ rightg,
                                              float* __restrict__ X)
{
  __shared__ ushort Ab[128 * 32];   // [row][k] bf16, rows 64B
  __shared__ ushort Bb[128 * 32];
  const int t = threadIdx.x, lane = t & 63, w = t >> 6;
  const int b = blockIdx.x;
  const int c = b & 127, tile = b >> 7;          // all tiles of a channel on one XCD
  const int tm = (tile >> 2) * 128, tn = (tile & 3) * 128;
  const ushort* Lc = leftg  + (size_t)c * N2;
  const ushort* Rc = rightg + (size_t)c * N2;
  float* Xc = X + (size_t)c * N2;
  const int wr = w >> 1, wc = w & 1, cl = lane & 15, h = lane >> 4;

  f32x4 acc[4][4];
  const f32x4 z = {0.f, 0.f, 0.f, 0.f};
  #pragma unroll
  for (int m = 0; m < 4; ++m)
    #pragma unroll
    for (int n = 0; n < 4; ++n) acc[m][n] = z;

  for (int kt = 0; kt < 16; ++kt){
    __syncthreads();
    #pragma unroll
    for (int s = 0; s < 2; ++s){
      const int q = w + 4 * s;                 // 8 chunks of 1KB per tile
      const int o = q * 1024 + lane * 16;
      const int row = o >> 6, kb = o & 63;
      gld_lds16((const char*)Lc + (size_t)(tm + row) * 1024 + kt * 64 + kb,
                (char*)Ab + q * 1024);
      gld_lds16((const char*)Rc + (size_t)(tn + row) * 1024 + kt * 64 + kb,
                (char*)Bb + q * 1024);
    }
    __syncthreads();
    s16x8 a[4], bf[4];
    #pragma unroll
    for (int m = 0; m < 4; ++m)
      a[m] = *(const s16x8*)&Ab[(wr*64 + m*16 + cl) * 32 + h * 8];
    #pragma unroll
    for (int n = 0; n < 4; ++n)
      bf[n] = *(const s16x8*)&Bb[(wc*64 + n*16 + cl) * 32 + h * 8];
    #pragma unroll
    for (int m = 0; m < 4; ++m)
      #pragma unroll
      for (int n = 0; n < 4; ++n)
        acc[m][n] = __builtin_amdgcn_mfma_f32_16x16x32_bf16(a[m], bf[n], acc[m][n], 0, 0, 0);
  }

  #pragma unroll
  for (int m = 0; m < 4; ++m)
    #pragma unroll
    for (int n = 0; n < 4; ++n)
      #pragma unroll
      for (int r = 0; r < 4; ++r)
        Xc[(size_t)(tm + wr*64 + m*16 + h*4 + r) * NRES + tn + wc*64 + n*16 + cl] =
            acc[m][n][r];
}

// -------------------- kernel 3: LN + out projection * gate ------------------
__global__ __launch_bounds__(256) void k3_out(
    const float* __restrict__ X, const ushort* __restrict__ gateg,
    const ushort* __restrict__ Wt5,
    const float* __restrict__ ln_g, const float* __restrict__ ln_b,
    const float* __restrict__ ob, float* __restrict__ out)
{
  __shared__ ushort Alds[128 * 136];
  __shared__ ushort Wlds[128 * 136];
  __shared__ float part[8][2][128];
  __shared__ float stat[2][128];
  const int t = threadIdx.x;
  const int p0 = blockIdx.x * 128;
  const int g = t >> 5, j = t & 31;

  float4 xv[16];
  float s0 = 0, s1 = 0, s2 = 0, s3 = 0, q0 = 0, q1 = 0, q2 = 0, q3 = 0;
  #pragma unroll
  for (int i = 0; i < 16; ++i){
    const int cch = g + (i << 3);
    xv[i] = *(const float4*)(X + (size_t)cch * N2 + p0 + j * 4);
    s0 += xv[i].x; q0 += xv[i].x * xv[i].x;
    s1 += xv[i].y; q1 += xv[i].y * xv[i].y;
    s2 += xv[i].z; q2 += xv[i].z * xv[i].z;
    s3 += xv[i].w; q3 += xv[i].w * xv[i].w;
  }
  part[g][0][j*4+0] = s0; part[g][0][j*4+1] = s1;
  part[g][0][j*4+2] = s2; part[g][0][j*4+3] = s3;
  part[g][1][j*4+0] = q0; part[g][1][j*4+1] = q1;
  part[g][1][j*4+2] = q2; part[g][1][j*4+3] = q3;
  __syncthreads();
  if (t < 128){
    float s = 0, q = 0;
    #pragma unroll
    for (int gg = 0; gg < 8; ++gg){ s += part[gg][0][t]; q += part[gg][1][t]; }
    float mu = s * (1.0f / 128.0f);
    float rs = rsqrtf(q * (1.0f / 128.0f) - mu * mu + 1e-5f);
    stat[0][t] = mu; stat[1][t] = rs;
  }
  __syncthreads();
  #pragma unroll
  for (int i = 0; i < 16; ++i){
    const int cch = g + (i << 3);
    const float gc = ln_g[cch], bc = ln_b[cch];
    const int p = j * 4;
    Alds[(p+0) * 136 + cch] = f2bf((xv[i].x - stat[0][p+0]) * stat[1][p+0] * gc + bc);
    Alds[(p+1) * 136 + cch] = f2bf((xv[i].y - stat[0][p+1]) * stat[1][p+1] * gc + bc);
    Alds[(p+2) * 136 + cch] = f2bf((xv[i].z - stat[0][p+2]) * stat[1][p+2] * gc + bc);
    Alds[(p+3) * 136 + cch] = f2bf((xv[i].w - stat[0][p+3]) * stat[1][p+3] * gc + bc);
  }
  // stage out_w into LDS [n][k]
  {
    #pragma unroll
    for (int u = 0; u < 8; ++u){
      int f = t + u * 256;
      int n = f >> 4, k8 = f & 15;
      *(s16x8*)&Wlds[n * 136 + k8 * 8] = *(const s16x8*)(Wt5 + f * 8);
    }
  }
  __syncthreads();

  const int lane = t & 63, w = t >> 6;
  const int wr = w >> 1, wc = w & 1, cl = lane & 15, h = lane >> 4;
  f32x4 acc[4][4];
  const f32x4 z = {0.f, 0.f, 0.f, 0.f};
  #pragma unroll
  for (int m = 0; m < 4; ++m)
    #pragma unroll
    for (int n = 0; n < 4; ++n) acc[m][n] = z;
  #pragma unroll
  for (int ks = 0; ks < 4; ++ks){
    s16x8 a[4], b[4];
    #pragma unroll
    for (int m = 0; m < 4; ++m)
      a[m] = *(const s16x8*)&Alds[(wr*64 + m*16 + cl) * 136 + ks*32 + h*8];
    #pragma unroll
    for (int n = 0; n < 4; ++n)
      b[n] = *(const s16x8*)&Wlds[(wc*64 + n*16 + cl) * 136 + ks*32 + h*8];
    #pragma unroll
    for (int m = 0; m < 4; ++m)
      #pragma unroll
      for (int n = 0; n < 4; ++n)
        acc[m][n] = __builtin_amdgcn_mfma_f32_16x16x32_bf16(a[m], b[n], acc[m][n], 0, 0, 0);
  }

  float obv[4];
  #pragma unroll
  for (int n = 0; n < 4; ++n) obv[n] = ob[wc*64 + n*16 + cl];
  #pragma unroll
  for (int m = 0; m < 4; ++m)
    #pragma unroll
    for (int n = 0; n < 4; ++n){
      const int cc = wc*64 + n*16 + cl;
      #pragma unroll
      for (int r = 0; r < 4; ++r){
        const size_t p = p0 + wr*64 + m*16 + h*4 + r;
        out[p * 128 + cc] = (acc[m][n][r] + obv[n]) * bf2f(gateg[p * 128 + cc]);
      }
    }
}

// -------------------- launcher ----------------------------------------------
extern "C" void kernel_launch(void* const* d_in, const int* in_sizes, int n_in,
                              void* d_out, int out_size, void* d_ws, size_t ws_size,
                              hipStream_t stream)
{
  const float* act    = (const float*)d_in[0];
  const float* mask   = (const float*)d_in[1];
  const float* ln_in_g = (const float*)d_in[2];
  const float* ln_in_b = (const float*)d_in[3];
  const float* lp_w = (const float*)d_in[4];
  const float* lp_b = (const float*)d_in[5];
  const float* rp_w = (const float*)d_in[6];
  const float* rp_b = (const float*)d_in[7];
  const float* lg_w = (const float*)d_in[8];
  const float* lg_b = (const float*)d_in[9];
  const float* rg_w = (const float*)d_in[10];
  const float* rg_b = (const float*)d_in[11];
  const float* ln_c_g = (const float*)d_in[12];
  const float* ln_c_b = (const float*)d_in[13];
  const float* out_w  = (const float*)d_in[14];
  const float* out_b  = (const float*)d_in[15];
  const float* gate_w = (const float*)d_in[16];
  const float* gate_b = (const float*)d_in[17];
  float* outp = (float*)d_out;

  char* ws = (char*)d_ws;
  ushort* Wt     = (ushort*)(ws);                                  // 196608 B
  ushort* leftg  = (ushort*)(ws + 196608);                         // 64 MB
  ushort* rightg = (ushort*)(ws + 196608 + 67108864ull);           // 64 MB
  ushort* gateg  = (ushort*)(ws + 196608 + 2ull * 67108864ull);    // 64 MB
  float*  X      = (float*) (ws + 196608 + 3ull * 67108864ull);    // 128 MB

  k0_prep<<<dim3(6), dim3(256), 0, stream>>>(lp_w, lg_w, rp_w, rg_w, gate_w, out_w, Wt);
  k1_proj<<<dim3(2048), dim3(256), 0, stream>>>(act, mask, ln_in_g, ln_in_b,
                                                lp_b, lg_b, rp_b, rg_b, gate_b,
                                                Wt, leftg, rightg, gateg);
  k2_tri<<<dim3(2048), dim3(256), 0, stream>>>(leftg, rightg, X);
  k3_out<<<dim3(2048), dim3(256), 0, stream>>>(X, gateg, Wt + 5 * 16384,
                                               ln_c_g, ln_c_b, out_b, outp);
}

// Round 3
// 516.504 us; speedup vs baseline: 1.1715x; 1.1239x over previous
//
#include <hip/hip_runtime.h>

#define NRES 512
#define N2   262144   // 512*512

typedef __attribute__((ext_vector_type(8))) short s16x8;
typedef __attribute__((ext_vector_type(4))) float f32x4;

__device__ __forceinline__ ushort f2bf(float x){
  union { float f; unsigned u; } v; v.f = x;
  unsigned r = (v.u + 0x7FFFu + ((v.u >> 16) & 1u)) >> 16;
  return (ushort)r;
}
__device__ __forceinline__ float bf2f(ushort h){
  union { unsigned u; float f; } v; v.u = ((unsigned)h) << 16; return v.f;
}
__device__ __forceinline__ float sigm(float x){ return 1.0f / (1.0f + __expf(-x)); }

__device__ __forceinline__ void gld_lds16(const void* g, void* lds){
  __builtin_amdgcn_global_load_lds((const __attribute__((address_space(1))) void*)g,
                                   (__attribute__((address_space(3))) void*)lds, 16, 0, 0);
}

// -------------------- kernel 0: weight transpose+convert --------------------
// Wt[m][n][k] = bf16(W_m[k][n]),  m in {lp, lg, rp, rg, gate, out}
__global__ void k0_prep(const float* __restrict__ lp, const float* __restrict__ lg,
                        const float* __restrict__ rp, const float* __restrict__ rg,
                        const float* __restrict__ gw, const float* __restrict__ ow,
                        ushort* __restrict__ Wt)
{
  const float* srcs[6] = {lp, lg, rp, rg, gw, ow};
  const float* wsrc = srcs[blockIdx.x];
  ushort* dst = Wt + blockIdx.x * 16384;
  for (int f = threadIdx.x; f < 16384; f += blockDim.x){
    int n = f >> 7, k = f & 127;
    dst[f] = f2bf(wsrc[k * 128 + n]);
  }
}

// -------------------- kernel 1: LN + 5 projections, reg-resident weights ----
// 512 threads = 8 waves; wave w owns columns [w*16, w*16+16) of ALL 5
// projection matrices. 20 weight fragments (80 VGPR) loaded once at start
// (hidden under LN). No global loads inside MFMA loops; one barrier total.
// left/right/gate all stored channel-major [c][p].
__global__ __launch_bounds__(512) void k1_proj(
    const float* __restrict__ act,  const float* __restrict__ mask,
    const float* __restrict__ ln_g, const float* __restrict__ ln_b,
    const float* __restrict__ lp_b, const float* __restrict__ lg_b,
    const float* __restrict__ rp_b, const float* __restrict__ rg_b,
    const float* __restrict__ gate_b, const ushort* __restrict__ Wt,
    ushort* __restrict__ leftg, ushort* __restrict__ rightg,
    ushort* __restrict__ gateg)
{
  __shared__ ushort Alds[128 * 136];      // 34816 B
  const int t  = threadIdx.x;
  const int p0 = blockIdx.x * 128;
  const int lane = t & 63, w = t >> 6;
  const int cl = lane & 15, h = lane >> 4;
  const int c  = w * 16 + cl;             // this wave's output channel

  // ---- all 5 weight slabs into registers (L2-resident source) ----
  s16x8 wf[5][4];
  #pragma unroll
  for (int m5 = 0; m5 < 5; ++m5)
    #pragma unroll
    for (int ks = 0; ks < 4; ++ks)
      wf[m5][ks] = *(const s16x8*)(Wt + (size_t)m5 * 16384 + (size_t)c * 128 + ks * 32 + h * 8);
  const float pb_l = lp_b[c], gb_l = lg_b[c];
  const float pb_r = rp_b[c], gb_r = rg_b[c];
  const float gb_g = gate_b[c];

  // ---- input layernorm -> bf16 A tile in LDS ----
  {
    const int g = t >> 5, j = t & 31;
    const float4 gv = *(const float4*)(ln_g + j * 4);
    const float4 bv = *(const float4*)(ln_b + j * 4);
    #pragma unroll
    for (int i = 0; i < 8; ++i){
      const int r = g + (i << 4);
      float4 v = *(const float4*)(act + (size_t)(p0 + r) * 128 + j * 4);
      float s = v.x + v.y + v.z + v.w;
      float q = v.x*v.x + v.y*v.y + v.z*v.z + v.w*v.w;
      #pragma unroll
      for (int m = 1; m < 32; m <<= 1){ s += __shfl_xor(s, m); q += __shfl_xor(q, m); }
      float mu = s * (1.0f / 128.0f);
      float rs = rsqrtf(q * (1.0f / 128.0f) - mu * mu + 1e-5f);
      ushort4 o;
      o.x = f2bf((v.x - mu) * rs * gv.x + bv.x);
      o.y = f2bf((v.y - mu) * rs * gv.y + bv.y);
      o.z = f2bf((v.z - mu) * rs * gv.z + bv.z);
      o.w = f2bf((v.w - mu) * rs * gv.w + bv.w);
      *(ushort4*)&Alds[r * 136 + j * 4] = o;
    }
  }
  __syncthreads();      // the only barrier

  const f32x4 z = {0.f, 0.f, 0.f, 0.f};

  #pragma unroll
  for (int mh = 0; mh < 2; ++mh){
    s16x8 a[4][4];
    #pragma unroll
    for (int m = 0; m < 4; ++m)
      #pragma unroll
      for (int ks = 0; ks < 4; ++ks)
        a[m][ks] = *(const s16x8*)&Alds[(mh*64 + m*16 + cl) * 136 + ks*32 + h*8];

    float mk[4][4];
    #pragma unroll
    for (int m = 0; m < 4; ++m)
      #pragma unroll
      for (int r = 0; r < 4; ++r)
        mk[m][r] = mask[p0 + mh*64 + m*16 + h*4 + r];

    // ---- left ----
    {
      f32x4 accP[4], accG[4];
      #pragma unroll
      for (int m = 0; m < 4; ++m){ accP[m] = z; accG[m] = z; }
      #pragma unroll
      for (int ks = 0; ks < 4; ++ks)
        #pragma unroll
        for (int m = 0; m < 4; ++m){
          accP[m] = __builtin_amdgcn_mfma_f32_16x16x32_bf16(a[m][ks], wf[0][ks], accP[m], 0, 0, 0);
          accG[m] = __builtin_amdgcn_mfma_f32_16x16x32_bf16(a[m][ks], wf[1][ks], accG[m], 0, 0, 0);
        }
      #pragma unroll
      for (int m = 0; m < 4; ++m){
        ushort4 o;
        o.x = f2bf(mk[m][0] * (accP[m][0] + pb_l) * sigm(accG[m][0] + gb_l));
        o.y = f2bf(mk[m][1] * (accP[m][1] + pb_l) * sigm(accG[m][1] + gb_l));
        o.z = f2bf(mk[m][2] * (accP[m][2] + pb_l) * sigm(accG[m][2] + gb_l));
        o.w = f2bf(mk[m][3] * (accP[m][3] + pb_l) * sigm(accG[m][3] + gb_l));
        *(ushort4*)(leftg + (size_t)c * N2 + p0 + mh*64 + m*16 + h*4) = o;
      }
    }
    // ---- right ----
    {
      f32x4 accP[4], accG[4];
      #pragma unroll
      for (int m = 0; m < 4; ++m){ accP[m] = z; accG[m] = z; }
      #pragma unroll
      for (int ks = 0; ks < 4; ++ks)
        #pragma unroll
        for (int m = 0; m < 4; ++m){
          accP[m] = __builtin_amdgcn_mfma_f32_16x16x32_bf16(a[m][ks], wf[2][ks], accP[m], 0, 0, 0);
          accG[m] = __builtin_amdgcn_mfma_f32_16x16x32_bf16(a[m][ks], wf[3][ks], accG[m], 0, 0, 0);
        }
      #pragma unroll
      for (int m = 0; m < 4; ++m){
        ushort4 o;
        o.x = f2bf(mk[m][0] * (accP[m][0] + pb_r) * sigm(accG[m][0] + gb_r));
        o.y = f2bf(mk[m][1] * (accP[m][1] + pb_r) * sigm(accG[m][1] + gb_r));
        o.z = f2bf(mk[m][2] * (accP[m][2] + pb_r) * sigm(accG[m][2] + gb_r));
        o.w = f2bf(mk[m][3] * (accP[m][3] + pb_r) * sigm(accG[m][3] + gb_r));
        *(ushort4*)(rightg + (size_t)c * N2 + p0 + mh*64 + m*16 + h*4) = o;
      }
    }
    // ---- gate (channel-major too) ----
    {
      f32x4 acc[4];
      #pragma unroll
      for (int m = 0; m < 4; ++m) acc[m] = z;
      #pragma unroll
      for (int ks = 0; ks < 4; ++ks)
        #pragma unroll
        for (int m = 0; m < 4; ++m)
          acc[m] = __builtin_amdgcn_mfma_f32_16x16x32_bf16(a[m][ks], wf[4][ks], acc[m], 0, 0, 0);
      #pragma unroll
      for (int m = 0; m < 4; ++m){
        ushort4 o;
        o.x = f2bf(sigm(acc[m][0] + gb_g));
        o.y = f2bf(sigm(acc[m][1] + gb_g));
        o.z = f2bf(sigm(acc[m][2] + gb_g));
        o.w = f2bf(sigm(acc[m][3] + gb_g));
        *(ushort4*)(gateg + (size_t)c * N2 + p0 + mh*64 + m*16 + h*4) = o;
      }
    }
  }
}

// -------------------- kernel 2: per-channel NT GEMM (triangle) --------------
// X[c][i][j] = sum_k left[c][i][k] * right[c][j][k];  X stored bf16.
// 2-phase double-buffered pipeline; XOR source-pre-swizzle on 16B chunks.
__global__ __launch_bounds__(256) void k2_tri(const ushort* __restrict__ leftg,
                                              const ushort* __restrict__ rightg,
                                              ushort* __restrict__ X)
{
  __shared__ ushort Ab[2][128 * 32];
  __shared__ ushort Bb[2][128 * 32];
  const int t = threadIdx.x, lane = t & 63, w = t >> 6;
  const int b = blockIdx.x;
  const int c = b & 127, tile = b >> 7;          // all tiles of a channel on one XCD
  const int tm = (tile >> 2) * 128, tn = (tile & 3) * 128;
  const char* Lc = (const char*)(leftg  + (size_t)c * N2);
  const char* Rc = (const char*)(rightg + (size_t)c * N2);
  ushort* Xc = X + (size_t)c * N2;
  const int wr = w >> 1, wc = w & 1, cl = lane & 15, h = lane >> 4;

  // staging geometry: linear LDS dest, XOR-swizzled global source
  const int o0 = (w    ) * 1024 + lane * 16;
  const int o1 = (w + 4) * 1024 + lane * 16;
  const int row0 = o0 >> 6, row1 = o1 >> 6;
  const int sk0 = ((((o0 >> 4) & 3) ^ (row0 & 3)) << 4);
  const int sk1 = ((((o1 >> 4) & 3) ^ (row1 & 3)) << 4);

  f32x4 acc[4][4];
  const f32x4 z = {0.f, 0.f, 0.f, 0.f};
  #pragma unroll
  for (int m = 0; m < 4; ++m)
    #pragma unroll
    for (int n = 0; n < 4; ++n) acc[m][n] = z;

  auto stage = [&](int buf, int kt){
    gld_lds16(Lc + (size_t)(tm + row0) * 1024 + kt * 64 + sk0, (char*)&Ab[buf][0] + o0);
    gld_lds16(Lc + (size_t)(tm + row1) * 1024 + kt * 64 + sk1, (char*)&Ab[buf][0] + o1);
    gld_lds16(Rc + (size_t)(tn + row0) * 1024 + kt * 64 + sk0, (char*)&Bb[buf][0] + o0);
    gld_lds16(Rc + (size_t)(tn + row1) * 1024 + kt * 64 + sk1, (char*)&Bb[buf][0] + o1);
  };
  const int rsw = ((h ^ (cl & 3)) << 4);   // swizzled read chunk
  auto compute = [&](int buf){
    s16x8 a2[4], b2[4];
    #pragma unroll
    for (int m = 0; m < 4; ++m)
      a2[m] = *(const s16x8*)((const char*)&Ab[buf][0] + (wr*64 + m*16 + cl) * 64 + rsw);
    #pragma unroll
    for (int n = 0; n < 4; ++n)
      b2[n] = *(const s16x8*)((const char*)&Bb[buf][0] + (wc*64 + n*16 + cl) * 64 + rsw);
    #pragma unroll
    for (int m = 0; m < 4; ++m)
      #pragma unroll
      for (int n = 0; n < 4; ++n)
        acc[m][n] = __builtin_amdgcn_mfma_f32_16x16x32_bf16(a2[m], b2[n], acc[m][n], 0, 0, 0);
  };

  stage(0, 0);
  __syncthreads();
  int cur = 0;
  for (int kt = 0; kt < 15; ++kt){
    stage(cur ^ 1, kt + 1);    // issue next tile: latency hides under compute
    compute(cur);
    __syncthreads();           // drains vmcnt AFTER the MFMAs
    cur ^= 1;
  }
  compute(cur);

  #pragma unroll
  for (int m = 0; m < 4; ++m)
    #pragma unroll
    for (int n = 0; n < 4; ++n)
      #pragma unroll
      for (int r = 0; r < 4; ++r)
        Xc[(size_t)(tm + wr*64 + m*16 + h*4 + r) * NRES + tn + wc*64 + n*16 + cl] =
            f2bf(acc[m][n][r]);
}

// -------------------- kernel 3: LN + out projection * gate ------------------
__global__ __launch_bounds__(256) void k3_out(
    const ushort* __restrict__ X, const ushort* __restrict__ gateg,
    const ushort* __restrict__ Wt5,
    const float* __restrict__ ln_g, const float* __restrict__ ln_b,
    const float* __restrict__ ob, float* __restrict__ out)
{
  __shared__ ushort Alds[128 * 136];
  __shared__ ushort Wlds[128 * 136];
  __shared__ float part[8][2][128];
  __shared__ float stat[2][128];
  const int t = threadIdx.x;
  const int p0 = blockIdx.x * 128;
  const int g = t >> 5, j = t & 31;

  float4 xv[16];
  float s0 = 0, s1 = 0, s2 = 0, s3 = 0, q0 = 0, q1 = 0, q2 = 0, q3 = 0;
  #pragma unroll
  for (int i = 0; i < 16; ++i){
    const int cch = g + (i << 3);
    ushort4 u4 = *(const ushort4*)(X + (size_t)cch * N2 + p0 + j * 4);
    xv[i].x = bf2f(u4.x); xv[i].y = bf2f(u4.y);
    xv[i].z = bf2f(u4.z); xv[i].w = bf2f(u4.w);
    s0 += xv[i].x; q0 += xv[i].x * xv[i].x;
    s1 += xv[i].y; q1 += xv[i].y * xv[i].y;
    s2 += xv[i].z; q2 += xv[i].z * xv[i].z;
    s3 += xv[i].w; q3 += xv[i].w * xv[i].w;
  }
  part[g][0][j*4+0] = s0; part[g][0][j*4+1] = s1;
  part[g][0][j*4+2] = s2; part[g][0][j*4+3] = s3;
  part[g][1][j*4+0] = q0; part[g][1][j*4+1] = q1;
  part[g][1][j*4+2] = q2; part[g][1][j*4+3] = q3;
  __syncthreads();
  if (t < 128){
    float s = 0, q = 0;
    #pragma unroll
    for (int gg = 0; gg < 8; ++gg){ s += part[gg][0][t]; q += part[gg][1][t]; }
    float mu = s * (1.0f / 128.0f);
    float rs = rsqrtf(q * (1.0f / 128.0f) - mu * mu + 1e-5f);
    stat[0][t] = mu; stat[1][t] = rs;
  }
  __syncthreads();
  #pragma unroll
  for (int i = 0; i < 16; ++i){
    const int cch = g + (i << 3);
    const float gc = ln_g[cch], bc = ln_b[cch];
    const int p = j * 4;
    Alds[(p+0) * 136 + cch] = f2bf((xv[i].x - stat[0][p+0]) * stat[1][p+0] * gc + bc);
    Alds[(p+1) * 136 + cch] = f2bf((xv[i].y - stat[0][p+1]) * stat[1][p+1] * gc + bc);
    Alds[(p+2) * 136 + cch] = f2bf((xv[i].z - stat[0][p+2]) * stat[1][p+2] * gc + bc);
    Alds[(p+3) * 136 + cch] = f2bf((xv[i].w - stat[0][p+3]) * stat[1][p+3] * gc + bc);
  }
  // stage out_w into LDS [n][k]
  #pragma unroll
  for (int u = 0; u < 8; ++u){
    int f = t + u * 256;
    int n = f >> 4, k8 = f & 15;
    *(s16x8*)&Wlds[n * 136 + k8 * 8] = *(const s16x8*)(Wt5 + f * 8);
  }
  __syncthreads();

  const int lane = t & 63, w = t >> 6;
  const int wr = w >> 1, wc = w & 1, cl = lane & 15, h = lane >> 4;
  f32x4 acc[4][4];
  const f32x4 z = {0.f, 0.f, 0.f, 0.f};
  #pragma unroll
  for (int m = 0; m < 4; ++m)
    #pragma unroll
    for (int n = 0; n < 4; ++n) acc[m][n] = z;
  #pragma unroll
  for (int ks = 0; ks < 4; ++ks){
    s16x8 a[4], bfr[4];
    #pragma unroll
    for (int m = 0; m < 4; ++m)
      a[m] = *(const s16x8*)&Alds[(wr*64 + m*16 + cl) * 136 + ks*32 + h*8];
    #pragma unroll
    for (int n = 0; n < 4; ++n)
      bfr[n] = *(const s16x8*)&Wlds[(wc*64 + n*16 + cl) * 136 + ks*32 + h*8];
    #pragma unroll
    for (int m = 0; m < 4; ++m)
      #pragma unroll
      for (int n = 0; n < 4; ++n)
        acc[m][n] = __builtin_amdgcn_mfma_f32_16x16x32_bf16(a[m], bfr[n], acc[m][n], 0, 0, 0);
  }

  float obv[4];
  #pragma unroll
  for (int n = 0; n < 4; ++n) obv[n] = ob[wc*64 + n*16 + cl];
  #pragma unroll
  for (int m = 0; m < 4; ++m)
    #pragma unroll
    for (int n = 0; n < 4; ++n){
      const int cc = wc*64 + n*16 + cl;
      ushort4 g4 = *(const ushort4*)(gateg + (size_t)cc * N2 + p0 + wr*64 + m*16 + h*4);
      const size_t pbase = p0 + wr*64 + m*16 + h*4;
      out[(pbase+0) * 128 + cc] = (acc[m][n][0] + obv[n]) * bf2f(g4.x);
      out[(pbase+1) * 128 + cc] = (acc[m][n][1] + obv[n]) * bf2f(g4.y);
      out[(pbase+2) * 128 + cc] = (acc[m][n][2] + obv[n]) * bf2f(g4.z);
      out[(pbase+3) * 128 + cc] = (acc[m][n][3] + obv[n]) * bf2f(g4.w);
    }
}

// -------------------- launcher ----------------------------------------------
extern "C" void kernel_launch(void* const* d_in, const int* in_sizes, int n_in,
                              void* d_out, int out_size, void* d_ws, size_t ws_size,
                              hipStream_t stream)
{
  const float* act    = (const float*)d_in[0];
  const float* mask   = (const float*)d_in[1];
  const float* ln_in_g = (const float*)d_in[2];
  const float* ln_in_b = (const float*)d_in[3];
  const float* lp_w = (const float*)d_in[4];
  const float* lp_b = (const float*)d_in[5];
  const float* rp_w = (const float*)d_in[6];
  const float* rp_b = (const float*)d_in[7];
  const float* lg_w = (const float*)d_in[8];
  const float* lg_b = (const float*)d_in[9];
  const float* rg_w = (const float*)d_in[10];
  const float* rg_b = (const float*)d_in[11];
  const float* ln_c_g = (const float*)d_in[12];
  const float* ln_c_b = (const float*)d_in[13];
  const float* out_w  = (const float*)d_in[14];
  const float* out_b  = (const float*)d_in[15];
  const float* gate_w = (const float*)d_in[16];
  const float* gate_b = (const float*)d_in[17];
  float* outp = (float*)d_out;

  char* ws = (char*)d_ws;
  ushort* Wt     = (ushort*)(ws);                                  // 196608 B
  ushort* leftg  = (ushort*)(ws + 196608);                         // 64 MB
  ushort* rightg = (ushort*)(ws + 196608 + 67108864ull);           // 64 MB
  ushort* gateg  = (ushort*)(ws + 196608 + 2ull * 67108864ull);    // 64 MB
  ushort* X      = (ushort*)(ws + 196608 + 3ull * 67108864ull);    // 64 MB

  k0_prep<<<dim3(6), dim3(256), 0, stream>>>(lp_w, lg_w, rp_w, rg_w, gate_w, out_w, Wt);
  k1_proj<<<dim3(2048), dim3(512), 0, stream>>>(act, mask, ln_in_g, ln_in_b,
                                                lp_b, lg_b, rp_b, rg_b, gate_b,
                                                Wt, leftg, rightg, gateg);
  k2_tri<<<dim3(2048), dim3(256), 0, stream>>>(leftg, rightg, X);
  k3_out<<<dim3(2048), dim3(256), 0, stream>>>(X, gateg, Wt + 5 * 16384,
                                               ln_c_g, ln_c_b, out_b, outp);
}

// Round 6
// 514.551 us; speedup vs baseline: 1.1760x; 1.0038x over previous
//
#include <hip/hip_runtime.h>

#define NRES 512
#define N2   262144   // 512*512

typedef __attribute__((ext_vector_type(8))) short s16x8;
typedef __attribute__((ext_vector_type(4))) float f32x4;

__device__ __forceinline__ ushort f2bf(float x){
  union { float f; unsigned u; } v; v.f = x;
  unsigned r = (v.u + 0x7FFFu + ((v.u >> 16) & 1u)) >> 16;
  return (ushort)r;
}
__device__ __forceinline__ float bf2f(ushort h){
  union { unsigned u; float f; } v; v.u = ((unsigned)h) << 16; return v.f;
}
__device__ __forceinline__ unsigned pkbf(float lo, float hi){
  unsigned r;
  asm volatile("v_cvt_pk_bf16_f32 %0, %1, %2" : "=v"(r) : "v"(lo), "v"(hi));
  return r;
}
__device__ __forceinline__ float sigm(float x){ return 1.0f / (1.0f + __expf(-x)); }

__device__ __forceinline__ void gld_lds16(const void* g, void* lds){
  __builtin_amdgcn_global_load_lds((const __attribute__((address_space(1))) void*)g,
                                   (__attribute__((address_space(3))) void*)lds, 16, 0, 0);
}

// -------------------- kernel 0: weight transpose+convert --------------------
__global__ void k0_prep(const float* __restrict__ lp, const float* __restrict__ lg,
                        const float* __restrict__ rp, const float* __restrict__ rg,
                        const float* __restrict__ gw, const float* __restrict__ ow,
                        ushort* __restrict__ Wt)
{
  const float* srcs[6] = {lp, lg, rp, rg, gw, ow};
  const float* wsrc = srcs[blockIdx.x];
  ushort* dst = Wt + blockIdx.x * 16384;
  for (int f = threadIdx.x; f < 16384; f += blockDim.x){
    int n = f >> 7, k = f & 127;
    dst[f] = f2bf(wsrc[k * 128 + n]);
  }
}

// -------------------- kernel 1: LN + 5 projections, reg-resident weights ----
// 8 waves; wave w owns columns [w*16, w*16+16) of ALL 5 matrices; weights in
// registers. Epilogue: per-wave LDS transpose -> full-line 64B global stores.
__global__ __launch_bounds__(512) void k1_proj(
    const float* __restrict__ act,  const float* __restrict__ mask,
    const float* __restrict__ ln_g, const float* __restrict__ ln_b,
    const float* __restrict__ lp_b, const float* __restrict__ lg_b,
    const float* __restrict__ rp_b, const float* __restrict__ rg_b,
    const float* __restrict__ gate_b, const ushort* __restrict__ Wt,
    ushort* __restrict__ leftg, ushort* __restrict__ rightg,
    ushort* __restrict__ gateg)
{
  __shared__ ushort Alds[128 * 136];       // 34816 B
  __shared__ ushort Scr[8][16 * 72];       // per-wave transpose scratch, 18432 B
  const int t  = threadIdx.x;
  const int p0 = blockIdx.x * 128;
  const int lane = t & 63, w = t >> 6;
  const int cl = lane & 15, h = lane >> 4;
  const int c  = w * 16 + cl;              // this wave's output channel

  // ---- all 5 weight slabs into registers (L2-resident source) ----
  s16x8 wf[5][4];
  #pragma unroll
  for (int m5 = 0; m5 < 5; ++m5)
    #pragma unroll
    for (int ks = 0; ks < 4; ++ks)
      wf[m5][ks] = *(const s16x8*)(Wt + (size_t)m5 * 16384 + (size_t)c * 128 + ks * 32 + h * 8);
  const float pb_l = lp_b[c], gb_l = lg_b[c];
  const float pb_r = rp_b[c], gb_r = rg_b[c];
  const float gb_g = gate_b[c];

  // ---- input layernorm -> bf16 A tile in LDS ----
  {
    const int g = t >> 5, j = t & 31;
    const float4 gv = *(const float4*)(ln_g + j * 4);
    const float4 bv = *(const float4*)(ln_b + j * 4);
    #pragma unroll
    for (int i = 0; i < 8; ++i){
      const int r = g + (i << 4);
      float4 v = *(const float4*)(act + (size_t)(p0 + r) * 128 + j * 4);
      float s = v.x + v.y + v.z + v.w;
      float q = v.x*v.x + v.y*v.y + v.z*v.z + v.w*v.w;
      #pragma unroll
      for (int m = 1; m < 32; m <<= 1){ s += __shfl_xor(s, m); q += __shfl_xor(q, m); }
      float mu = s * (1.0f / 128.0f);
      float rs = rsqrtf(q * (1.0f / 128.0f) - mu * mu + 1e-5f);
      uint2 o;
      o.x = pkbf((v.x - mu) * rs * gv.x + bv.x, (v.y - mu) * rs * gv.y + bv.y);
      o.y = pkbf((v.z - mu) * rs * gv.z + bv.z, (v.w - mu) * rs * gv.w + bv.w);
      *(uint2*)&Alds[r * 136 + j * 4] = o;
    }
  }
  __syncthreads();      // the only barrier

  ushort* scr = &Scr[w][0];
  const int rc = lane >> 2, rq = lane & 3;   // readback channel / quarter
  const f32x4 z = {0.f, 0.f, 0.f, 0.f};

  #pragma unroll
  for (int mh = 0; mh < 2; ++mh){
    s16x8 a[4][4];
    #pragma unroll
    for (int m = 0; m < 4; ++m)
      #pragma unroll
      for (int ks = 0; ks < 4; ++ks)
        a[m][ks] = *(const s16x8*)&Alds[(mh*64 + m*16 + cl) * 136 + ks*32 + h*8];

    float mk[4][4];
    #pragma unroll
    for (int m = 0; m < 4; ++m)
      #pragma unroll
      for (int r = 0; r < 4; ++r)
        mk[m][r] = mask[p0 + mh*64 + m*16 + h*4 + r];

    // per-wave transpose store: scr write -> linear readback -> 64B-line stores
    auto wv_store = [&](const uint2 v[4], ushort* dstg){
      #pragma unroll
      for (int m = 0; m < 4; ++m)
        *(uint2*)&scr[cl * 72 + m * 16 + h * 4] = v[m];
      asm volatile("s_waitcnt lgkmcnt(0)" ::: "memory");
      s16x8 r0 = *(const s16x8*)&scr[rc * 72 + rq * 16];
      s16x8 r1 = *(const s16x8*)&scr[rc * 72 + rq * 16 + 8];
      *(s16x8*)(dstg + (size_t)rc * N2 + rq * 16)     = r0;
      *(s16x8*)(dstg + (size_t)rc * N2 + rq * 16 + 8) = r1;
    };
    const size_t doff = (size_t)(w * 16) * N2 + p0 + mh * 64;

    // ---- left ----
    {
      f32x4 accP[4], accG[4];
      #pragma unroll
      for (int m = 0; m < 4; ++m){ accP[m] = z; accG[m] = z; }
      #pragma unroll
      for (int ks = 0; ks < 4; ++ks)
        #pragma unroll
        for (int m = 0; m < 4; ++m){
          accP[m] = __builtin_amdgcn_mfma_f32_16x16x32_bf16(a[m][ks], wf[0][ks], accP[m], 0, 0, 0);
          accG[m] = __builtin_amdgcn_mfma_f32_16x16x32_bf16(a[m][ks], wf[1][ks], accG[m], 0, 0, 0);
        }
      uint2 o[4];
      #pragma unroll
      for (int m = 0; m < 4; ++m){
        float x0 = mk[m][0] * (accP[m][0] + pb_l) * sigm(accG[m][0] + gb_l);
        float x1 = mk[m][1] * (accP[m][1] + pb_l) * sigm(accG[m][1] + gb_l);
        float x2 = mk[m][2] * (accP[m][2] + pb_l) * sigm(accG[m][2] + gb_l);
        float x3 = mk[m][3] * (accP[m][3] + pb_l) * sigm(accG[m][3] + gb_l);
        o[m].x = pkbf(x0, x1); o[m].y = pkbf(x2, x3);
      }
      wv_store(o, leftg + doff);
    }
    // ---- right ----
    {
      f32x4 accP[4], accG[4];
      #pragma unroll
      for (int m = 0; m < 4; ++m){ accP[m] = z; accG[m] = z; }
      #pragma unroll
      for (int ks = 0; ks < 4; ++ks)
        #pragma unroll
        for (int m = 0; m < 4; ++m){
          accP[m] = __builtin_amdgcn_mfma_f32_16x16x32_bf16(a[m][ks], wf[2][ks], accP[m], 0, 0, 0);
          accG[m] = __builtin_amdgcn_mfma_f32_16x16x32_bf16(a[m][ks], wf[3][ks], accG[m], 0, 0, 0);
        }
      uint2 o[4];
      #pragma unroll
      for (int m = 0; m < 4; ++m){
        float x0 = mk[m][0] * (accP[m][0] + pb_r) * sigm(accG[m][0] + gb_r);
        float x1 = mk[m][1] * (accP[m][1] + pb_r) * sigm(accG[m][1] + gb_r);
        float x2 = mk[m][2] * (accP[m][2] + pb_r) * sigm(accG[m][2] + gb_r);
        float x3 = mk[m][3] * (accP[m][3] + pb_r) * sigm(accG[m][3] + gb_r);
        o[m].x = pkbf(x0, x1); o[m].y = pkbf(x2, x3);
      }
      wv_store(o, rightg + doff);
    }
    // ---- gate ----
    {
      f32x4 acc[4];
      #pragma unroll
      for (int m = 0; m < 4; ++m) acc[m] = z;
      #pragma unroll
      for (int ks = 0; ks < 4; ++ks)
        #pragma unroll
        for (int m = 0; m < 4; ++m)
          acc[m] = __builtin_amdgcn_mfma_f32_16x16x32_bf16(a[m][ks], wf[4][ks], acc[m], 0, 0, 0);
      uint2 o[4];
      #pragma unroll
      for (int m = 0; m < 4; ++m){
        o[m].x = pkbf(sigm(acc[m][0] + gb_g), sigm(acc[m][1] + gb_g));
        o[m].y = pkbf(sigm(acc[m][2] + gb_g), sigm(acc[m][3] + gb_g));
      }
      wv_store(o, gateg + doff);
    }
  }
}

// -------------------- kernel 2: per-channel NT GEMM (triangle) --------------
__global__ __launch_bounds__(256) void k2_tri(const ushort* __restrict__ leftg,
                                              const ushort* __restrict__ rightg,
                                              ushort* __restrict__ X)
{
  __shared__ ushort Ab[2][128 * 32];
  __shared__ ushort Bb[2][128 * 32];
  const int t = threadIdx.x, lane = t & 63, w = t >> 6;
  const int b = blockIdx.x;
  const int c = b & 127, tile = b >> 7;
  const int tm = (tile >> 2) * 128, tn = (tile & 3) * 128;
  const char* Lc = (const char*)(leftg  + (size_t)c * N2);
  const char* Rc = (const char*)(rightg + (size_t)c * N2);
  ushort* Xc = X + (size_t)c * N2;
  const int wr = w >> 1, wc = w & 1, cl = lane & 15, h = lane >> 4;

  const int o0 = (w    ) * 1024 + lane * 16;
  const int o1 = (w + 4) * 1024 + lane * 16;
  const int row0 = o0 >> 6, row1 = o1 >> 6;
  const int sk0 = ((((o0 >> 4) & 3) ^ (row0 & 3)) << 4);
  const int sk1 = ((((o1 >> 4) & 3) ^ (row1 & 3)) << 4);

  f32x4 acc[4][4];
  const f32x4 z = {0.f, 0.f, 0.f, 0.f};
  #pragma unroll
  for (int m = 0; m < 4; ++m)
    #pragma unroll
    for (int n = 0; n < 4; ++n) acc[m][n] = z;

  auto stage = [&](int buf, int kt){
    gld_lds16(Lc + (size_t)(tm + row0) * 1024 + kt * 64 + sk0, (char*)&Ab[buf][0] + o0);
    gld_lds16(Lc + (size_t)(tm + row1) * 1024 + kt * 64 + sk1, (char*)&Ab[buf][0] + o1);
    gld_lds16(Rc + (size_t)(tn + row0) * 1024 + kt * 64 + sk0, (char*)&Bb[buf][0] + o0);
    gld_lds16(Rc + (size_t)(tn + row1) * 1024 + kt * 64 + sk1, (char*)&Bb[buf][0] + o1);
  };
  const int rsw = ((h ^ (cl & 3)) << 4);
  auto compute = [&](int buf){
    s16x8 a2[4], b2[4];
    #pragma unroll
    for (int m = 0; m < 4; ++m)
      a2[m] = *(const s16x8*)((const char*)&Ab[buf][0] + (wr*64 + m*16 + cl) * 64 + rsw);
    #pragma unroll
    for (int n = 0; n < 4; ++n)
      b2[n] = *(const s16x8*)((const char*)&Bb[buf][0] + (wc*64 + n*16 + cl) * 64 + rsw);
    #pragma unroll
    for (int m = 0; m < 4; ++m)
      #pragma unroll
      for (int n = 0; n < 4; ++n)
        acc[m][n] = __builtin_amdgcn_mfma_f32_16x16x32_bf16(a2[m], b2[n], acc[m][n], 0, 0, 0);
  };

  stage(0, 0);
  __syncthreads();
  int cur = 0;
  for (int kt = 0; kt < 15; ++kt){
    stage(cur ^ 1, kt + 1);
    compute(cur);
    __syncthreads();
    cur ^= 1;
  }
  compute(cur);

  #pragma unroll
  for (int m = 0; m < 4; ++m)
    #pragma unroll
    for (int n = 0; n < 4; ++n)
      #pragma unroll
      for (int r = 0; r < 4; ++r)
        Xc[(size_t)(tm + wr*64 + m*16 + h*4 + r) * NRES + tn + wc*64 + n*16 + cl] =
            f2bf(acc[m][n][r]);
}

// -------------------- kernel 3: LN + out projection * gate ------------------
__global__ __launch_bounds__(256) void k3_out(
    const ushort* __restrict__ X, const ushort* __restrict__ gateg,
    const ushort* __restrict__ Wt5,
    const float* __restrict__ ln_g, const float* __restrict__ ln_b,
    const float* __restrict__ ob, float* __restrict__ out)
{
  __shared__ ushort Alds[128 * 136];
  __shared__ ushort Wlds[128 * 136];
  __shared__ float part[8][2][128];
  __shared__ float stat[2][128];
  const int t = threadIdx.x;
  const int p0 = blockIdx.x * 128;
  const int g = t >> 5, j = t & 31;

  float4 xv[16];
  float s0 = 0, s1 = 0, s2 = 0, s3 = 0, q0 = 0, q1 = 0, q2 = 0, q3 = 0;
  #pragma unroll
  for (int i = 0; i < 16; ++i){
    const int cch = g + (i << 3);
    ushort4 u4 = *(const ushort4*)(X + (size_t)cch * N2 + p0 + j * 4);
    xv[i].x = bf2f(u4.x); xv[i].y = bf2f(u4.y);
    xv[i].z = bf2f(u4.z); xv[i].w = bf2f(u4.w);
    s0 += xv[i].x; q0 += xv[i].x * xv[i].x;
    s1 += xv[i].y; q1 += xv[i].y * xv[i].y;
    s2 += xv[i].z; q2 += xv[i].z * xv[i].z;
    s3 += xv[i].w; q3 += xv[i].w * xv[i].w;
  }
  part[g][0][j*4+0] = s0; part[g][0][j*4+1] = s1;
  part[g][0][j*4+2] = s2; part[g][0][j*4+3] = s3;
  part[g][1][j*4+0] = q0; part[g][1][j*4+1] = q1;
  part[g][1][j*4+2] = q2; part[g][1][j*4+3] = q3;
  __syncthreads();
  if (t < 128){
    float s = 0, q = 0;
    #pragma unroll
    for (int gg = 0; gg < 8; ++gg){ s += part[gg][0][t]; q += part[gg][1][t]; }
    float mu = s * (1.0f / 128.0f);
    float rs = rsqrtf(q * (1.0f / 128.0f) - mu * mu + 1e-5f);
    stat[0][t] = mu; stat[1][t] = rs;
  }
  __syncthreads();
  #pragma unroll
  for (int i = 0; i < 16; ++i){
    const int cch = g + (i << 3);
    const float gc = ln_g[cch], bc = ln_b[cch];
    const int p = j * 4;
    Alds[(p+0) * 136 + cch] = f2bf((xv[i].x - stat[0][p+0]) * stat[1][p+0] * gc + bc);
    Alds[(p+1) * 136 + cch] = f2bf((xv[i].y - stat[0][p+1]) * stat[1][p+1] * gc + bc);
    Alds[(p+2) * 136 + cch] = f2bf((xv[i].z - stat[0][p+2]) * stat[1][p+2] * gc + bc);
    Alds[(p+3) * 136 + cch] = f2bf((xv[i].w - stat[0][p+3]) * stat[1][p+3] * gc + bc);
  }
  #pragma unroll
  for (int u = 0; u < 8; ++u){
    int f = t + u * 256;
    int n = f >> 4, k8 = f & 15;
    *(s16x8*)&Wlds[n * 136 + k8 * 8] = *(const s16x8*)(Wt5 + f * 8);
  }
  __syncthreads();

  const int lane = t & 63, w = t >> 6;
  const int wr = w >> 1, wc = w & 1, cl = lane & 15, h = lane >> 4;
  f32x4 acc[4][4];
  const f32x4 z = {0.f, 0.f, 0.f, 0.f};
  #pragma unroll
  for (int m = 0; m < 4; ++m)
    #pragma unroll
    for (int n = 0; n < 4; ++n) acc[m][n] = z;
  #pragma unroll
  for (int ks = 0; ks < 4; ++ks){
    s16x8 a[4], bfr[4];
    #pragma unroll
    for (int m = 0; m < 4; ++m)
      a[m] = *(const s16x8*)&Alds[(wr*64 + m*16 + cl) * 136 + ks*32 + h*8];
    #pragma unroll
    for (int n = 0; n < 4; ++n)
      bfr[n] = *(const s16x8*)&Wlds[(wc*64 + n*16 + cl) * 136 + ks*32 + h*8];
    #pragma unroll
    for (int m = 0; m < 4; ++m)
      #pragma unroll
      for (int n = 0; n < 4; ++n)
        acc[m][n] = __builtin_amdgcn_mfma_f32_16x16x32_bf16(a[m], bfr[n], acc[m][n], 0, 0, 0);
  }

  float obv[4];
  #pragma unroll
  for (int n = 0; n < 4; ++n) obv[n] = ob[wc*64 + n*16 + cl];
  #pragma unroll
  for (int m = 0; m < 4; ++m)
    #pragma unroll
    for (int n = 0; n < 4; ++n){
      const int cc = wc*64 + n*16 + cl;
      ushort4 g4 = *(const ushort4*)(gateg + (size_t)cc * N2 + p0 + wr*64 + m*16 + h*4);
      const size_t pbase = p0 + wr*64 + m*16 + h*4;
      out[(pbase+0) * 128 + cc] = (acc[m][n][0] + obv[n]) * bf2f(g4.x);
      out[(pbase+1) * 128 + cc] = (acc[m][n][1] + obv[n]) * bf2f(g4.y);
      out[(pbase+2) * 128 + cc] = (acc[m][n][2] + obv[n]) * bf2f(g4.z);
      out[(pbase+3) * 128 + cc] = (acc[m][n][3] + obv[n]) * bf2f(g4.w);
    }
}

// -------------------- launcher ----------------------------------------------
extern "C" void kernel_launch(void* const* d_in, const int* in_sizes, int n_in,
                              void* d_out, int out_size, void* d_ws, size_t ws_size,
                              hipStream_t stream)
{
  const float* act    = (const float*)d_in[0];
  const float* mask   = (const float*)d_in[1];
  const float* ln_in_g = (const float*)d_in[2];
  const float* ln_in_b = (const float*)d_in[3];
  const float* lp_w = (const float*)d_in[4];
  const float* lp_b = (const float*)d_in[5];
  const float* rp_w = (const float*)d_in[6];
  const float* rp_b = (const float*)d_in[7];
  const float* lg_w = (const float*)d_in[8];
  const float* lg_b = (const float*)d_in[9];
  const float* rg_w = (const float*)d_in[10];
  const float* rg_b = (const float*)d_in[11];
  const float* ln_c_g = (const float*)d_in[12];
  const float* ln_c_b = (const float*)d_in[13];
  const float* out_w  = (const float*)d_in[14];
  const float* out_b  = (const float*)d_in[15];
  const float* gate_w = (const float*)d_in[16];
  const float* gate_b = (const float*)d_in[17];
  float* outp = (float*)d_out;

  char* ws = (char*)d_ws;
  ushort* Wt     = (ushort*)(ws);                                  // 196608 B
  ushort* leftg  = (ushort*)(ws + 196608);                         // 64 MB
  ushort* rightg = (ushort*)(ws + 196608 + 67108864ull);           // 64 MB
  ushort* gateg  = (ushort*)(ws + 196608 + 2ull * 67108864ull);    // 64 MB
  ushort* X      = (ushort*)(ws + 196608 + 3ull * 67108864ull);    // 64 MB

  k0_prep<<<dim3(6), dim3(256), 0, stream>>>(lp_w, lg_w, rp_w, rg_w, gate_w, out_w, Wt);
  k1_proj<<<dim3(2048), dim3(512), 0, stream>>>(act, mask, ln_in_g, ln_in_b,
                                                lp_b, lg_b, rp_b, rg_b, gate_b,
                                                Wt, leftg, rightg, gateg);
  k2_tri<<<dim3(2048), dim3(256), 0, stream>>>(leftg, rightg, X);
  k3_out<<<dim3(2048), dim3(256), 0, stream>>>(X, gateg, Wt + 5 * 16384,
                                               ln_c_g, ln_c_b, out_b, outp);
}